// Round 19
// baseline (202.013 us; speedup 1.0000x reference)
//
#include <hip/hip_runtime.h>
#include <math.h>

#define CH 256
#define GRP 16
#define EPSV 1e-5f
#define BB 4

typedef __attribute__((ext_vector_type(8))) short short8;
typedef __attribute__((ext_vector_type(4))) short short4v;
typedef __attribute__((ext_vector_type(4))) float f32x4;

__device__ __forceinline__ float hsig(float x){
  return fminf(fmaxf((x + 3.0f) * (1.0f/6.0f), 0.0f), 1.0f);
}

__device__ __forceinline__ unsigned short f2bf(float f){
  union { float f; unsigned int u; } v; v.f = f;
  unsigned int r = v.u + 0x7fffu + ((v.u >> 16) & 1u);
  return (unsigned short)(r >> 16);
}

__device__ __forceinline__ float bf2f(unsigned short u){
  union { float f; unsigned int i; } v; v.i = ((unsigned int)u) << 16; return v.f;
}

__device__ __forceinline__ void gload_lds16(const void* g, void* l){
  __builtin_amdgcn_global_load_lds((const __attribute__((address_space(1))) unsigned int*)g,
                                   (__attribute__((address_space(3))) unsigned int*)l, 16, 0, 0);
}

// ---------------- prep: weight packing + NHWC transpose + rowsum, fused -------
__global__ __launch_bounds__(256) void prep_kernel(
    const float* __restrict__ w_mid, const float* __restrict__ w_low, const float* __restrict__ w_high,
    const float* __restrict__ w_off,
    const float* __restrict__ x0, const float* __restrict__ x1, const float* __restrict__ x2,
    unsigned short* __restrict__ Wm, unsigned short* __restrict__ Wl, unsigned short* __restrict__ Wh,
    unsigned short* __restrict__ W27,
    float* __restrict__ xn0, float* __restrict__ xn1, float* __restrict__ xn2,
    float* __restrict__ roww0, float* __restrict__ roww1){
  __shared__ float lds[32][257];
  int blk = blockIdx.x;
  int t = threadIdx.x;
  if (blk < 6912){
    const float* w = (blk < 2304) ? w_mid : (blk < 4608 ? w_low : w_high);
    unsigned short* W3 = (blk < 2304) ? Wm : (blk < 4608 ? Wl : Wh);
    int idx = (blk % 2304) * 256 + t;   // 0..589823
    int e = idx & 7;
    int l = (idx >> 3) & 63;
    int f = idx >> 9;            // s*16 + q*4 + mf
    int mf = f & 3;
    int q = (f >> 2) & 3;
    int s = f >> 4;              // 0..71
    int kk = s >> 3, cb = s & 7;
    int o = q * 64 + mf * 16 + (l & 15);
    int kc = ((l >> 4) << 3) + e;
    int c = cb * 32 + kc;
    W3[idx] = f2bf(w[(o * CH + c) * 9 + kk]);
    return;
  }
  if (blk < 7200){
    int idx = (blk - 6912) * 256 + t;   // 0..73727
    int s = idx >> 10;
    int r = idx & 1023;
    int o = r >> 5;
    int pos = r & 31;
    int cp = pos >> 3, j = pos & 7;
    int kc = ((cp ^ ((o >> 1) & 3)) << 3) + j;
    int kk = s >> 3, cb = s & 7;
    int c = (cb << 5) + kc;
    W27[idx] = (o < 27) ? f2bf(w_off[(o * CH + c) * 9 + kk]) : (unsigned short)0;
    return;
  }
  if (blk >= 7872){
    float* out = (blk == 7873) ? roww1 : roww0;
    int Hh = (blk == 7873) ? 16 : 32;
    int H = (blk == 7873) ? 32 : 64;
    if (t < Hh){
      float rs = 0.0f;
      float scale = (float)(Hh - 1) / (float)(H - 1);
      for (int h = 0; h < H; h++){
        float ysv = (float)h * scale;
        float y0f = floorf(ysv);
        int y0 = (int)y0f;
        float fy = ysv - y0f;
        int y1 = min(y0 + 1, Hh - 1);
        if (y0 == t) rs += 1.0f - fy;
        if (y1 == t) rs += fy;
      }
      out[t] = rs;
    }
    return;
  }
  int nb = blk - 7200;   // 0..671
  const float* xs; float* xd; int HW; int rb;
  if (nb < 512){ xs = x0; xd = xn0; HW = 4096; rb = nb; }
  else if (nb < 640){ xs = x1; xd = xn1; HW = 1024; rb = nb - 512; }
  else { xs = x2; xd = xn2; HW = 256; rb = nb - 640; }
  int p0 = rb * 32;
  int b = p0 / HW;
  int rem0 = p0 - b * HW;
  int pl = t & 31, cg = t >> 5;
  for (int ci = 0; ci < 32; ci++){
    int c = ci * 8 + cg;
    lds[pl][c] = xs[(long)(b * CH + c) * HW + rem0 + pl];
  }
  __syncthreads();
  for (int p = 0; p < 32; p++){
    xd[(long)(b * HW + rem0 + p) * CH + t] = lds[p][t];
  }
}

// ---------------- offset conv (all levels fused), 4-lane/pixel gather ---------
__global__ __launch_bounds__(256, 4) void conv_offset_mfma_kernel(
    const float* __restrict__ xn0, const float* __restrict__ xn1, const float* __restrict__ xn2,
    const unsigned short* __restrict__ W27, const float* __restrict__ boff,
    float* __restrict__ offs_all, float* __restrict__ mask_all){
  __shared__ __align__(16) short awlds[1024];
  __shared__ __align__(16) short cbuf[4096];
  int blk = blockIdx.x;
  const float* xn; int H; long ooff, moff; int rb;
  if (blk < 256){ xn = xn0; H = 64; ooff = 0; moff = 0; rb = blk; }
  else if (blk < 320){ xn = xn1; H = 32; ooff = 294912; moff = 147456; rb = blk - 256; }
  else { xn = xn2; H = 16; ooff = 368640; moff = 184320; rb = blk - 320; }
  int W = H, HW = H * W;
  int t = threadIdx.x;
  int lane = t & 63, wv = t >> 6;
  int pxp = t >> 2, cgp = t & 3;
  int pg = rb * 64 + pxp;
  int b = pg / HW;
  int rem = pg - b * HW;
  int i = rem / W, j = rem - i * W;

  f32x4 acc[2];
  #pragma unroll
  for (int mf = 0; mf < 2; mf++){
    #pragma unroll
    for (int r = 0; r < 4; r++){
      int o = mf * 16 + (lane >> 4) * 4 + r;
      acc[mf][r] = boff[o < 27 ? o : 0];
    }
  }

  for (int kk = 0; kk < 9; kk++){
    int ky = kk / 3, kx = kk - ky * 3;
    int ii = i - 1 + ky, jj = j - 1 + kx;
    bool valid = (ii >= 0 && ii < H && jj >= 0 && jj < W);
    int addr = valid ? ((b * HW + ii * W + jj) << 8) : 0;
    float vm = valid ? 1.0f : 0.0f;
    for (int cb8 = 0; cb8 < 8; cb8++){
      __syncthreads();
      const unsigned short* tile = W27 + (size_t)(kk * 8 + cb8) * 1024;
      if (t < 128) gload_lds16(tile + (t >> 6) * 512 + (t & 63) * 8, (short*)awlds + (t >> 6) * 512);
      const float* xc = xn + addr + cb8 * 32 + cgp * 8;
      float4 va = *(const float4*)xc;
      float4 vb = *(const float4*)(xc + 4);
      short8 pk;
      pk[0] = (short)f2bf(vm * va.x); pk[1] = (short)f2bf(vm * va.y);
      pk[2] = (short)f2bf(vm * va.z); pk[3] = (short)f2bf(vm * va.w);
      pk[4] = (short)f2bf(vm * vb.x); pk[5] = (short)f2bf(vm * vb.y);
      pk[6] = (short)f2bf(vm * vb.z); pk[7] = (short)f2bf(vm * vb.w);
      *(short8*)((char*)cbuf + pxp * 64 + ((cgp ^ ((pxp >> 1) & 3)) << 4)) = pk;
      __syncthreads();
      short8 af[2];
      #pragma unroll
      for (int mf = 0; mf < 2; mf++){
        int o = mf * 16 + (lane & 15);
        af[mf] = *(const short8*)((const char*)awlds + o * 64 + ((((lane >> 4)) ^ ((o >> 1) & 3)) << 4));
      }
      int nc = wv * 16 + (lane & 15);
      short8 bf1 = *(const short8*)((const char*)cbuf + nc * 64 + ((((lane >> 4)) ^ ((nc >> 1) & 3)) << 4));
      acc[0] = __builtin_amdgcn_mfma_f32_16x16x32_bf16(af[0], bf1, acc[0], 0, 0, 0);
      acc[1] = __builtin_amdgcn_mfma_f32_16x16x32_bf16(af[1], bf1, acc[1], 0, 0, 0);
    }
  }

  int rem0 = rb * 64 - b * HW;
  #pragma unroll
  for (int mf = 0; mf < 2; mf++){
    #pragma unroll
    for (int r = 0; r < 4; r++){
      int o = mf * 16 + (lane >> 4) * 4 + r;
      int pix = rem0 + wv * 16 + (lane & 15);
      float v = acc[mf][r];
      if (o < 18) offs_all[ooff + ((long)b * 18 + o) * HW + pix] = v;
      else if (o < 27) mask_all[moff + ((long)b * 9 + (o - 18)) * HW + pix] = 1.0f / (1.0f + expf(-v));
    }
  }
}

// ---------------- mdcn: 128px/512thr, bf16 y + fused per-tile channel stats ---
__device__ const int MJ_start[8] = {0,128,160,168,200,208,240,248};
__device__ const int MJ_xsel[7]  = {0,1,2,0,1,1,2};
__device__ const int MJ_Hx[7]    = {64,32,16,64,32,32,16};
__device__ const int MJ_ooff[7]  = {0,294912,368640,294912,368640,0,294912};
__device__ const int MJ_moff[7]  = {0,147456,184320,147456,184320,0,147456};
__device__ const int MJ_Hoff[7]  = {64,32,16,32,16,64,32};
__device__ const int MJ_ostep[7] = {1,1,1,1,1,2,2};
__device__ const int MJ_strd[7]  = {1,1,1,2,2,1,1};
__device__ const int MJ_wsel[7]  = {0,0,0,1,1,2,2};
__device__ const int MJ_yoff[7]  = {0,5242880,7602176,6291456,7864320,4194304,7340032};
__device__ const int MJ_Ho[7]    = {64,32,16,32,16,32,16};

__global__ __launch_bounds__(512, 2) void mdcn_mfma_kernel(
    const float* __restrict__ xn0, const float* __restrict__ xn1, const float* __restrict__ xn2,
    const float* __restrict__ offs_all, const float* __restrict__ mask_all,
    const unsigned short* __restrict__ Wm, const unsigned short* __restrict__ Wl, const unsigned short* __restrict__ Wh,
    const float* __restrict__ roww0, const float* __restrict__ roww1,
    unsigned short* __restrict__ y_all, float* __restrict__ gpart){
  __shared__ __align__(16) short colbuf[4][4096];  // 4 x 8 KB  B [128 px][32 kc]
  __shared__ float pstat[2][256][3];               // 6 KB epilogue stats

  int dd = (blockIdx.x & 7) * 31 + (blockIdx.x >> 3);
  int job = 0;
  while (job < 6 && dd >= MJ_start[job + 1]) job++;
  int xsel = MJ_xsel[job];
  const float* xn = (xsel == 0) ? xn0 : (xsel == 1 ? xn1 : xn2);
  int wsel = MJ_wsel[job];
  const unsigned short* W3 = (wsel == 0) ? Wm : (wsel == 1 ? Wl : Wh);
  int Hx = MJ_Hx[job], Wx = Hx, HxWx = Hx * Hx;
  int Ho = MJ_Ho[job], Wo = Ho, HoWo = Ho * Ho;
  int Woff = MJ_Hoff[job], HoffW = Woff * Woff;
  int ostep = MJ_ostep[job], stride = MJ_strd[job];
  const float* offs = offs_all + MJ_ooff[job];
  const float* maskb = mask_all + MJ_moff[job];
  unsigned short* y = y_all + MJ_yoff[job];

  int rb = dd - MJ_start[job];
  int blkPerB = HoWo >> 7;
  int b = rb / blkPerB;
  int n0 = (rb - b * blkPerB) << 7;

  int t = threadIdx.x;
  int lane = t & 63;
  int wv = t >> 6;
  int wq = wv >> 1;
  int px = t >> 2;
  int cg = t & 3;

  int pix = n0 + px;
  int i = pix / Wo, j = pix - i * Wo;
  int opos = i * ostep * Woff + j * ostep;
  int base = b * HxWx;

  int4 A4c, A4n; float4 Wtc, Wtn;
  auto computeAW = [&](int kk, int4& A4o, float4& Wto){
    int ky = kk / 3, kx = kk - ky * 3;
    float offy = offs[((long)b * 18 + 2 * kk) * HoffW + opos];
    float offx = offs[((long)b * 18 + 2 * kk + 1) * HoffW + opos];
    float m = maskb[((long)b * 9 + kk) * HoffW + opos];
    float py = (float)(i * stride - 1 + ky) + offy;
    float pxx = (float)(j * stride - 1 + kx) + offx;
    float y0f = floorf(py), x0f = floorf(pxx);
    float fy = py - y0f, fx = pxx - x0f;
    bool vy0 = (y0f >= 0.0f) && (y0f <= (float)(Hx - 1));
    bool vy1 = (y0f + 1.0f >= 0.0f) && (y0f + 1.0f <= (float)(Hx - 1));
    bool vx0 = (x0f >= 0.0f) && (x0f <= (float)(Wx - 1));
    bool vx1 = (x0f + 1.0f >= 0.0f) && (x0f + 1.0f <= (float)(Wx - 1));
    float w0 = (1.0f - fy) * (1.0f - fx) * m * ((vy0 && vx0) ? 1.0f : 0.0f);
    float w1 = (1.0f - fy) * fx * m * ((vy0 && vx1) ? 1.0f : 0.0f);
    float w2 = fy * (1.0f - fx) * m * ((vy1 && vx0) ? 1.0f : 0.0f);
    float w3 = fy * fx * m * ((vy1 && vx1) ? 1.0f : 0.0f);
    int iy0 = min(max((int)y0f, 0), Hx - 1);
    int iy1 = min(max((int)y0f + 1, 0), Hx - 1);
    int ix0 = min(max((int)x0f, 0), Wx - 1);
    int ix1 = min(max((int)x0f + 1, 0), Wx - 1);
    A4o = make_int4((base + iy0 * Wx + ix0) << 8, (base + iy0 * Wx + ix1) << 8,
                    (base + iy1 * Wx + ix0) << 8, (base + iy1 * Wx + ix1) << 8);
    Wto = make_float4(w0, w1, w2, w3);
  };

  float4 g0_0,g0_1,g0_2,g0_3,g0_4,g0_5,g0_6,g0_7;
  float4 g1_0,g1_1,g1_2,g1_3,g1_4,g1_5,g1_6,g1_7;

  short8 af0[4], af1[4];
  auto loadA = [&](int s, short8* af){
    const short8* wp = (const short8*)W3 + ((size_t)s * 16 + wq * 4) * 64 + lane;
    af[0] = wp[0]; af[1] = wp[64]; af[2] = wp[128]; af[3] = wp[192];
  };

  f32x4 acc[4][4];
  #pragma unroll
  for (int mf = 0; mf < 4; mf++)
    #pragma unroll
    for (int nf = 0; nf < 4; nf++)
      acc[mf][nf] = (f32x4){0.f, 0.f, 0.f, 0.f};

#define GATHER_(P, CB, A4G) do{ \
    const float* xc_ = xn + (CB)*32 + cg*8; \
    g##P##_0 = *(const float4*)(xc_ + (A4G).x); g##P##_1 = *(const float4*)(xc_ + (A4G).x + 4); \
    g##P##_2 = *(const float4*)(xc_ + (A4G).y); g##P##_3 = *(const float4*)(xc_ + (A4G).y + 4); \
    g##P##_4 = *(const float4*)(xc_ + (A4G).z); g##P##_5 = *(const float4*)(xc_ + (A4G).z + 4); \
    g##P##_6 = *(const float4*)(xc_ + (A4G).w); g##P##_7 = *(const float4*)(xc_ + (A4G).w + 4); \
  }while(0)

#define PACKW_(P, BUF, WT) do{ \
    short8 pk_; \
    pk_[0] = (short)f2bf((WT).x*g##P##_0.x + (WT).y*g##P##_2.x + (WT).z*g##P##_4.x + (WT).w*g##P##_6.x); \
    pk_[1] = (short)f2bf((WT).x*g##P##_0.y + (WT).y*g##P##_2.y + (WT).z*g##P##_4.y + (WT).w*g##P##_6.y); \
    pk_[2] = (short)f2bf((WT).x*g##P##_0.z + (WT).y*g##P##_2.z + (WT).z*g##P##_4.z + (WT).w*g##P##_6.z); \
    pk_[3] = (short)f2bf((WT).x*g##P##_0.w + (WT).y*g##P##_2.w + (WT).z*g##P##_4.w + (WT).w*g##P##_6.w); \
    pk_[4] = (short)f2bf((WT).x*g##P##_1.x + (WT).y*g##P##_3.x + (WT).z*g##P##_5.x + (WT).w*g##P##_7.x); \
    pk_[5] = (short)f2bf((WT).x*g##P##_1.y + (WT).y*g##P##_3.y + (WT).z*g##P##_5.y + (WT).w*g##P##_7.y); \
    pk_[6] = (short)f2bf((WT).x*g##P##_1.z + (WT).y*g##P##_3.z + (WT).z*g##P##_5.z + (WT).w*g##P##_7.z); \
    pk_[7] = (short)f2bf((WT).x*g##P##_1.w + (WT).y*g##P##_3.w + (WT).z*g##P##_5.w + (WT).w*g##P##_7.w); \
    *(short8*)((char*)colbuf[BUF] + px * 64 + ((cg ^ ((px >> 1) & 3)) << 4)) = pk_; \
  }while(0)

#define MFMA_(BUF, AF) do{ \
    __builtin_amdgcn_s_setprio(1); \
    short8 bf_[4]; \
    _Pragma("unroll") \
    for (int nf = 0; nf < 4; nf++){ \
      int nc_ = (wv & 1) * 64 + nf * 16 + (lane & 15); \
      bf_[nf] = *(const short8*)((const char*)colbuf[BUF] + nc_ * 64 + ((((lane >> 4)) ^ ((nc_ >> 1) & 3)) << 4)); } \
    _Pragma("unroll") \
    for (int mf = 0; mf < 4; mf++) \
      _Pragma("unroll") \
      for (int nf = 0; nf < 4; nf++) \
        acc[mf][nf] = __builtin_amdgcn_mfma_f32_16x16x32_bf16((AF)[mf], bf_[nf], acc[mf][nf], 0, 0, 0); \
    __builtin_amdgcn_s_setprio(0); \
  }while(0)

#define BARRIER_ do{ \
    asm volatile("s_waitcnt lgkmcnt(0)" ::: "memory"); \
    __builtin_amdgcn_sched_barrier(0); \
    __builtin_amdgcn_s_barrier(); \
    __builtin_amdgcn_sched_barrier(0); \
  }while(0)

#define PHASE_(P, PC, PN) do{ \
    if ((P) <= 34){ PACKW_(0, (PN), Wtc); PACKW_(1, (PN)+1, Wtc); } \
    if ((P) <= 33){ \
      if (((2*(P)+4) & 7) == 0){ \
        computeAW((2*(P)+4) >> 3, A4n, Wtn); \
        GATHER_(0, 0, A4n); \
        GATHER_(1, 1, A4n); \
      } else { \
        GATHER_(0, (2*(P)+4) & 7, A4c); \
        GATHER_(1, (2*(P)+5) & 7, A4c); \
      } \
    } \
    MFMA_((PC), af0); \
    MFMA_((PC)+1, af1); \
    if ((P) <= 34){ loadA(2*(P)+2, af0); loadA(2*(P)+3, af1); } \
    if ((P) <= 33 && ((2*(P)+4) & 7) == 0){ A4c = A4n; Wtc = Wtn; } \
    BARRIER_; \
  }while(0)

  computeAW(0, A4c, Wtc);
  loadA(0, af0);
  loadA(1, af1);
  GATHER_(0, 0, A4c);
  GATHER_(1, 1, A4c);
  PACKW_(0, 0, Wtc);
  PACKW_(1, 1, Wtc);
  GATHER_(0, 2, A4c);
  GATHER_(1, 3, A4c);
  BARRIER_;

  for (int pp = 0; pp < 36; pp += 2){
    PHASE_(pp, 0, 2);
    PHASE_(pp + 1, 2, 0);
  }

#undef PHASE_
#undef BARRIER_
#undef MFMA_
#undef PACKW_
#undef GATHER_

  // ---- epilogue: C write (bf16) + per-tile channel stats ----
  const float* rw = (job == 5) ? roww0 : ((job == 6) ? roww1 : (const float*)nullptr);
  int woLog = (Wo == 64) ? 6 : ((Wo == 32) ? 5 : 4);
  int nhalf = wv & 1;
  #pragma unroll
  for (int mf = 0; mf < 4; mf++){
    #pragma unroll
    for (int r = 0; r < 4; r++){
      int o = wq * 64 + mf * 16 + (lane >> 4) * 4 + r;
      float s = 0.0f, ss = 0.0f, ws = 0.0f;
      #pragma unroll
      for (int nf = 0; nf < 4; nf++){
        int pix2 = n0 + nhalf * 64 + nf * 16 + (lane & 15);
        unsigned short ub = f2bf(acc[mf][nf][r]);
        y[((long)b * CH + o) * HoWo + pix2] = ub;
        float vq = bf2f(ub);
        s += vq; ss += vq * vq;
        if (rw){
          int i2 = pix2 >> woLog, j2 = pix2 & (Wo - 1);
          ws += vq * rw[i2] * rw[j2];
        }
      }
      #pragma unroll
      for (int m2 = 1; m2 < 16; m2 <<= 1){
        s  += __shfl_xor(s, m2, 64);
        ss += __shfl_xor(ss, m2, 64);
        if (rw) ws += __shfl_xor(ws, m2, 64);
      }
      if ((lane & 15) == 0){
        pstat[nhalf][o][0] = s;
        pstat[nhalf][o][1] = ss;
        pstat[nhalf][o][2] = rw ? ws : 0.0f;
      }
    }
  }
  __syncthreads();
  if (t < 256){
    float s  = pstat[0][t][0] + pstat[1][t][0];
    float ss = pstat[0][t][1] + pstat[1][t][1];
    float ws = pstat[0][t][2] + pstat[1][t][2];
    float* gp = gpart + (size_t)dd * 768 + t * 3;
    gp[0] = s; gp[1] = ss; gp[2] = ws;
  }
}

// ---------------- reduce per-tile partials -> per-(slot,b,c) stats -----------
// SJ slot order: 0=mid0, 1=high0, 2=mid1, 3=low1, 4=high1, 5=mid2, 6=low2
__device__ const int SR_mj[7]      = {0, 5, 1, 3, 6, 2, 4};   // SJ slot -> MJ job
__device__ const int SR_tilesPB[7] = {32, 8, 8, 8, 2, 2, 2};  // blkPerB of that MJ job

__global__ __launch_bounds__(256) void stats_reduce_kernel(
    const float* __restrict__ gpart,
    float* __restrict__ sums_all, float* __restrict__ ss_all, float* __restrict__ wsum_all){
  int tid = blockIdx.x * 256 + threadIdx.x;   // 0..7167
  int sj = tid >> 10;
  int rem = tid & 1023;        // b*256 + c
  int b = rem >> 8;
  int c = rem & 255;
  int mj = SR_mj[sj];
  int tiles = SR_tilesPB[sj];
  int dd0 = MJ_start[mj] + b * tiles;
  float s = 0.0f, ss = 0.0f, ws = 0.0f;
  for (int ti = 0; ti < tiles; ti++){
    const float* gp = gpart + (size_t)(dd0 + ti) * 768 + c * 3;
    s += gp[0]; ss += gp[1]; ws += gp[2];
  }
  sums_all[sj * 1024 + rem] = s;
  ss_all[sj * 1024 + rem] = ss;
  if (sj == 1) wsum_all[rem] = ws;
  else if (sj == 4) wsum_all[1024 + rem] = ws;
}

// ---------------- group-norm stats + scale_attn, all 7 jobs fused -------------
__device__ const int   GJ_psrc[7] = {0,1,0,0,2,0,0};
__device__ const float GJ_pdiv[7] = {1.f/4096,1.f/4096,1.f/1024,1.f/1024,1.f/1024,1.f/256,1.f/256};
__device__ const float GJ_ninv[7] = {1.f/65536,1.f/16384,1.f/16384,1.f/16384,1.f/4096,1.f/4096,1.f/4096};
__device__ const int   GJ_gsel[7] = {0,2,0,1,2,0,1};

__global__ __launch_bounds__(256) void gn_sa_all_kernel(
    const float* __restrict__ sums_all, const float* __restrict__ ss_all, const float* __restrict__ wsum_all,
    const float* __restrict__ gw_m, const float* __restrict__ gb_m,
    const float* __restrict__ gw_l, const float* __restrict__ gb_l,
    const float* __restrict__ gw_h, const float* __restrict__ gb_h,
    const float* __restrict__ saw, const float* __restrict__ sab,
    float* __restrict__ mu_all, float* __restrict__ rs_all, float* __restrict__ v_all){
  int blk = blockIdx.x;
  int job = blk >> 2, b = blk & 3;
  int t = threadIdx.x;
  const float* sums = sums_all + job * 1024;
  const float* ssq  = ss_all + job * 1024;
  int psrc = GJ_psrc[job];
  const float* ps = (psrc == 0) ? sums : (wsum_all + (psrc - 1) * 1024);
  int gsel = GJ_gsel[job];
  const float* gw = (gsel == 0) ? gw_m : (gsel == 1 ? gw_l : gw_h);
  const float* gb = (gsel == 0) ? gb_m : (gsel == 1 ? gb_l : gb_h);
  float pdiv = GJ_pdiv[job], ninv = GJ_ninv[job];
  __shared__ float smu[GRP], srs[GRP], red[256];
  if (t < GRP){
    float s = 0, ss = 0;
    for (int c = 0; c < 16; c++){ int idx = b * CH + t * 16 + c; s += sums[idx]; ss += ssq[idx]; }
    float mu = s * ninv;
    float var = ss * ninv - mu * mu;
    float rs = rsqrtf(var + EPSV);
    smu[t] = mu; srs[t] = rs;
    mu_all[job * 64 + b * GRP + t] = mu;
    rs_all[job * 64 + b * GRP + t] = rs;
  }
  __syncthreads();
  int g = t >> 4;
  float pm = (ps[b * CH + t] * pdiv - smu[g]) * srs[g] * gw[t] + gb[t];
  red[t] = pm * saw[t];
  __syncthreads();
  for (int o = 128; o > 0; o >>= 1){ if (t < o) red[t] += red[t + o]; __syncthreads(); }
  if (t == 0) v_all[job * 4 + b] = hsig(fmaxf(red[0] + sab[0], 0.0f));
}

// GN-stat slot numbering: 0=mid0, 1=high0, 2=mid1, 3=low1, 4=high1, 5=mid2, 6=low2
__device__ const long CA_yb[3] = {0, 5242880, 7602176};
__device__ const long CA_yl[3] = {0, 6291456, 7864320};
__device__ const long CA_yh[3] = {4194304, 7340032, 0};
__device__ const int  CA_ms[3] = {0, 2, 5};
__device__ const int  CA_ls[3] = {0, 3, 6};
__device__ const int  CA_hs[3] = {1, 4, 0};
__device__ const long FA_out[3] = {0, 4194304, 5242880};

// ---------------- dyrelu coefficients computed analytically -------------------
__global__ __launch_bounds__(256) void dyrelu_direct_kernel(
    const float* __restrict__ sums_all, const float* __restrict__ wsum_all,
    const float* __restrict__ mu_all, const float* __restrict__ rs_all, const float* __restrict__ v_all,
    const float* __restrict__ gw_m, const float* __restrict__ gb_m,
    const float* __restrict__ gw_l, const float* __restrict__ gb_l,
    const float* __restrict__ gw_h, const float* __restrict__ gb_h,
    const float* __restrict__ w1, const float* __restrict__ b1,
    const float* __restrict__ w2, const float* __restrict__ b2,
    float* __restrict__ coef_all){
  int lvl = blockIdx.x >> 2, b = blockIdx.x & 3;
  int t = threadIdx.x;
  int H = 64 >> lvl, HW = H * H;
  float invHW = 1.0f / (float)HW;
  int has_lo = (lvl > 0), has_hi = (lvl < 2);
  float inv_cnt = 1.0f / (1.0f + has_lo + has_hi);
  int ms = CA_ms[lvl], ls = CA_ls[lvl], hs = CA_hs[lvl];
  int g = t >> 4;
  float p = v_all[ms * 4 + b] *
      ((sums_all[ms * 1024 + b * CH + t] * invHW - mu_all[ms * 64 + b * GRP + g]) * rs_all[ms * 64 + b * GRP + g] * gw_m[t] + gb_m[t]);
  if (has_lo)
    p += v_all[ls * 4 + b] *
      ((sums_all[ls * 1024 + b * CH + t] * invHW - mu_all[ls * 64 + b * GRP + g]) * rs_all[ls * 64 + b * GRP + g] * gw_l[t] + gb_l[t]);
  if (has_hi)
    p += v_all[hs * 4 + b] *
      ((wsum_all[lvl * 1024 + b * CH + t] * invHW - mu_all[hs * 64 + b * GRP + g]) * rs_all[hs * 64 + b * GRP + g] * gw_h[t] + gb_h[t]);
  p *= inv_cnt;
  __shared__ float pl[CH], hl[64];
  pl[t] = p;
  __syncthreads();
  if (t < 64){
    float a = b1[t];
    const float* wr = w1 + t * CH;
    for (int c = 0; c < CH; c++) a += wr[c] * pl[c];
    hl[t] = fmaxf(a, 0.0f);
  }
  __syncthreads();
  #pragma unroll
  for (int r = 0; r < 4; r++){
    int o = r * CH + t;
    float a = b2[o];
    const float* wr = w2 + o * 64;
    #pragma unroll
    for (int j = 0; j < 64; j++) a += wr[j] * hl[j];
    float co = hsig(a) - 0.5f;
    float outv;
    if (r == 0) outv = co * 2.0f + 1.0f;
    else if (r == 2) outv = co * 2.0f;
    else outv = co;
    coef_all[lvl * 4096 + (b * 4 + r) * CH + t] = outv;
  }
}

// ---------------- combine + dyrelu apply, fused, bf16 reads (4 px/thread) -----
__global__ __launch_bounds__(256) void combine_final_kernel(
    const unsigned short* __restrict__ y_all,
    const float* __restrict__ mu_all, const float* __restrict__ rs_all, const float* __restrict__ v_all,
    const float* __restrict__ gw_m, const float* __restrict__ gb_m,
    const float* __restrict__ gw_l, const float* __restrict__ gb_l,
    const float* __restrict__ gw_h, const float* __restrict__ gb_h,
    const float* __restrict__ coef_all, float* __restrict__ outp){
  int blk = blockIdx.x;
  int lvl, rb;
  if (blk < 4096){ lvl = 0; rb = blk; }
  else if (blk < 5120){ lvl = 1; rb = blk - 4096; }
  else { lvl = 2; rb = blk - 5120; }
  int H = 64 >> lvl, W = H, HW = H * W;
  int has_lo = (lvl > 0), has_hi = (lvl < 2);
  float inv_cnt = 1.0f / (1.0f + has_lo + has_hi);
  int ms = CA_ms[lvl], ls = CA_ls[lvl], hs = CA_hs[lvl];
  const unsigned short* smid = y_all + CA_yb[lvl];
  const unsigned short* ylo = y_all + CA_yl[lvl];
  const unsigned short* yhi = y_all + CA_yh[lvl];

  int t = threadIdx.x;
  int idx = (rb * 256 + t) * 4;
  int b = idx / (CH * HW);
  int r1i = idx - b * CH * HW;
  int c = r1i / HW;
  int rem = r1i - c * HW;
  int h = rem / W;
  int w = rem - h * W;
  int g = c >> 4;
  int bg = b * GRP + g;

  short4v m4 = *(const short4v*)(smid + idx);
  float vms = v_all[ms * 4 + b], mum = mu_all[ms * 64 + bg], rsm = rs_all[ms * 64 + bg];
  float gm = gw_m[c], bm = gb_m[c];
  float4 s4;
  s4.x = vms * ((bf2f((unsigned short)m4[0]) - mum) * rsm * gm + bm);
  s4.y = vms * ((bf2f((unsigned short)m4[1]) - mum) * rsm * gm + bm);
  s4.z = vms * ((bf2f((unsigned short)m4[2]) - mum) * rsm * gm + bm);
  s4.w = vms * ((bf2f((unsigned short)m4[3]) - mum) * rsm * gm + bm);
  if (has_lo){
    short4v l4 = *(const short4v*)(ylo + idx);
    float vls = v_all[ls * 4 + b], mul = mu_all[ls * 64 + bg], rsl = rs_all[ls * 64 + bg];
    float gl = gw_l[c], bl = gb_l[c];
    s4.x += vls * ((bf2f((unsigned short)l4[0]) - mul) * rsl * gl + bl);
    s4.y += vls * ((bf2f((unsigned short)l4[1]) - mul) * rsl * gl + bl);
    s4.z += vls * ((bf2f((unsigned short)l4[2]) - mul) * rsl * gl + bl);
    s4.w += vls * ((bf2f((unsigned short)l4[3]) - mul) * rsl * gl + bl);
  }
  if (has_hi){
    int Hh = H >> 1, Wh = W >> 1;
    float ysv = (float)h * ((float)(Hh - 1) / (float)(H - 1));
    float y0f = floorf(ysv); int y0 = (int)y0f; float fy = ysv - y0f; int y1 = min(y0 + 1, Hh - 1);
    const unsigned short* hb = yhi + (long)(b * CH + c) * Hh * Wh;
    float vhs = v_all[hs * 4 + b], muh = mu_all[hs * 64 + bg], rsh = rs_all[hs * 64 + bg];
    float gh = gw_h[c], bh = gb_h[c];
    float xscale = (float)(Wh - 1) / (float)(W - 1);
    float* sp = (float*)&s4;
    #pragma unroll
    for (int dw = 0; dw < 4; dw++){
      float xsv = (float)(w + dw) * xscale;
      float x0f = floorf(xsv); int x0 = (int)x0f; float fx = xsv - x0f; int x1 = min(x0 + 1, Wh - 1);
      float v00 = bf2f(hb[y0 * Wh + x0]), v01 = bf2f(hb[y0 * Wh + x1]);
      float v10 = bf2f(hb[y1 * Wh + x0]), v11 = bf2f(hb[y1 * Wh + x1]);
      float blv = v00 * (1 - fy) * (1 - fx) + v01 * (1 - fy) * fx + v10 * fy * (1 - fx) + v11 * fy * fx;
      sp[dw] += vhs * ((blv - muh) * rsh * gh + bh);
    }
  }
  const float* cf = coef_all + lvl * 4096 + b * 4 * CH;
  float a1 = cf[c], c1 = cf[CH + c], a2 = cf[2 * CH + c], c2 = cf[3 * CH + c];
  float4 o4;
  float sx = s4.x * inv_cnt, sy = s4.y * inv_cnt, sz = s4.z * inv_cnt, sw = s4.w * inv_cnt;
  o4.x = fmaxf(sx * a1 + c1, sx * a2 + c2);
  o4.y = fmaxf(sy * a1 + c1, sy * a2 + c2);
  o4.z = fmaxf(sz * a1 + c1, sz * a2 + c2);
  o4.w = fmaxf(sw * a1 + c1, sw * a2 + c2);
  *(float4*)(outp + FA_out[lvl] + idx) = o4;
}

extern "C" void kernel_launch(void* const* d_in, const int* in_sizes, int n_in,
                              void* d_out, int out_size, void* d_ws, size_t ws_size,
                              hipStream_t stream){
  const float* x0 = (const float*)d_in[0];
  const float* x1 = (const float*)d_in[1];
  const float* x2 = (const float*)d_in[2];
  const float* w_off = (const float*)d_in[3];
  const float* b_off = (const float*)d_in[4];
  int sig = (in_sizes[6] == 256);
  const float* w_high = (const float*)d_in[5];
  const float* w_mid  = (const float*)d_in[sig ? 8 : 6];
  const float* w_low  = (const float*)d_in[sig ? 11 : 7];
  const float* gn_high_w = (const float*)d_in[sig ? 6 : 8];
  const float* gn_high_b = (const float*)d_in[sig ? 7 : 9];
  const float* gn_mid_w  = (const float*)d_in[sig ? 9 : 10];
  const float* gn_mid_b  = (const float*)d_in[sig ? 10 : 11];
  const float* gn_low_w  = (const float*)d_in[12];
  const float* gn_low_b  = (const float*)d_in[13];
  const float* sa_w  = (const float*)d_in[14];
  const float* sa_b  = (const float*)d_in[15];
  const float* dy_w1 = (const float*)d_in[16];
  const float* dy_b1 = (const float*)d_in[17];
  const float* dy_w2 = (const float*)d_in[18];
  const float* dy_b2 = (const float*)d_in[19];

  float* p = (float*)d_ws;
  unsigned short* W3_mid  = (unsigned short*)p; p += 294912;
  unsigned short* W3_low  = (unsigned short*)p; p += 294912;
  unsigned short* W3_high = (unsigned short*)p; p += 294912;
  unsigned short* W27     = (unsigned short*)p; p += 36864;
  float* xn0 = p; p += 4194304;
  float* xn1 = p; p += 1048576;
  float* xn2 = p; p += 262144;
  float* offs_all = p; p += 387072;
  float* mask_all = p; p += 193536;
  unsigned short* y_all = (unsigned short*)p; p += 4063232;   // 8126464 bf16 elems
  float* gpart = p; p += 190464;                               // 248 tiles x 256 ch x 3
  float* sums_all = p; p += 7168;
  float* ss_all = p; p += 7168;
  float* wsum_all = p; p += 2048;
  float* coef_all = p; p += 12288;
  float* mu_all = p; p += 448;
  float* rs_all = p; p += 448;
  float* v_all = p; p += 28;   p += 4;  // align
  float* roww0 = p; p += 32;
  float* roww1 = p; p += 32;

  prep_kernel<<<7874, 256, 0, stream>>>(w_mid, w_low, w_high, w_off, x0, x1, x2,
                                        W3_mid, W3_low, W3_high, W27,
                                        xn0, xn1, xn2, roww0, roww1);
  conv_offset_mfma_kernel<<<336, 256, 0, stream>>>(xn0, xn1, xn2, W27, b_off, offs_all, mask_all);
  mdcn_mfma_kernel<<<248, 512, 0, stream>>>(xn0, xn1, xn2, offs_all, mask_all,
                                            W3_mid, W3_low, W3_high, roww0, roww1, y_all, gpart);
  stats_reduce_kernel<<<28, 256, 0, stream>>>(gpart, sums_all, ss_all, wsum_all);
  gn_sa_all_kernel<<<28, 256, 0, stream>>>(sums_all, ss_all, wsum_all,
                                           gn_mid_w, gn_mid_b, gn_low_w, gn_low_b, gn_high_w, gn_high_b,
                                           sa_w, sa_b, mu_all, rs_all, v_all);
  dyrelu_direct_kernel<<<12, 256, 0, stream>>>(sums_all, wsum_all, mu_all, rs_all, v_all,
                                               gn_mid_w, gn_mid_b, gn_low_w, gn_low_b, gn_high_w, gn_high_b,
                                               dy_w1, dy_b1, dy_w2, dy_b2, coef_all);
  combine_final_kernel<<<5376, 256, 0, stream>>>(y_all, mu_all, rs_all, v_all,
                                                 gn_mid_w, gn_mid_b, gn_low_w, gn_low_b, gn_high_w, gn_high_b,
                                                 coef_all, (float*)d_out);
}

// Round 20
// 195.696 us; speedup vs baseline: 1.0323x; 1.0323x over previous
//
#include <hip/hip_runtime.h>
#include <math.h>

#define CH 256
#define GRP 16
#define EPSV 1e-5f
#define BB 4

typedef __attribute__((ext_vector_type(8))) short short8;
typedef __attribute__((ext_vector_type(4))) short short4v;
typedef __attribute__((ext_vector_type(4))) float f32x4;

__device__ __forceinline__ float hsig(float x){
  return fminf(fmaxf((x + 3.0f) * (1.0f/6.0f), 0.0f), 1.0f);
}

__device__ __forceinline__ unsigned short f2bf(float f){
  union { float f; unsigned int u; } v; v.f = f;
  unsigned int r = v.u + 0x7fffu + ((v.u >> 16) & 1u);
  return (unsigned short)(r >> 16);
}

__device__ __forceinline__ float bf2f(unsigned short u){
  union { float f; unsigned int i; } v; v.i = ((unsigned int)u) << 16; return v.f;
}

__device__ __forceinline__ void gload_lds16(const void* g, void* l){
  __builtin_amdgcn_global_load_lds((const __attribute__((address_space(1))) unsigned int*)g,
                                   (__attribute__((address_space(3))) unsigned int*)l, 16, 0, 0);
}

// ---------------- prep: weight packing + NHWC transpose + rowsum, fused -------
__global__ __launch_bounds__(256) void prep_kernel(
    const float* __restrict__ w_mid, const float* __restrict__ w_low, const float* __restrict__ w_high,
    const float* __restrict__ w_off,
    const float* __restrict__ x0, const float* __restrict__ x1, const float* __restrict__ x2,
    unsigned short* __restrict__ Wm, unsigned short* __restrict__ Wl, unsigned short* __restrict__ Wh,
    unsigned short* __restrict__ W27,
    float* __restrict__ xn0, float* __restrict__ xn1, float* __restrict__ xn2,
    float* __restrict__ roww0, float* __restrict__ roww1){
  __shared__ float lds[32][257];
  int blk = blockIdx.x;
  int t = threadIdx.x;
  if (blk < 6912){
    const float* w = (blk < 2304) ? w_mid : (blk < 4608 ? w_low : w_high);
    unsigned short* W3 = (blk < 2304) ? Wm : (blk < 4608 ? Wl : Wh);
    int idx = (blk % 2304) * 256 + t;   // 0..589823
    int e = idx & 7;
    int l = (idx >> 3) & 63;
    int f = idx >> 9;            // s*16 + q*4 + mf
    int mf = f & 3;
    int q = (f >> 2) & 3;
    int s = f >> 4;              // 0..71
    int kk = s >> 3, cb = s & 7;
    int o = q * 64 + mf * 16 + (l & 15);
    int kc = ((l >> 4) << 3) + e;
    int c = cb * 32 + kc;
    W3[idx] = f2bf(w[(o * CH + c) * 9 + kk]);
    return;
  }
  if (blk < 7200){
    int idx = (blk - 6912) * 256 + t;   // 0..73727
    int s = idx >> 10;
    int r = idx & 1023;
    int o = r >> 5;
    int pos = r & 31;
    int cp = pos >> 3, j = pos & 7;
    int kc = ((cp ^ ((o >> 1) & 3)) << 3) + j;
    int kk = s >> 3, cb = s & 7;
    int c = (cb << 5) + kc;
    W27[idx] = (o < 27) ? f2bf(w_off[(o * CH + c) * 9 + kk]) : (unsigned short)0;
    return;
  }
  if (blk >= 7872){
    float* out = (blk == 7873) ? roww1 : roww0;
    int Hh = (blk == 7873) ? 16 : 32;
    int H = (blk == 7873) ? 32 : 64;
    if (t < Hh){
      float rs = 0.0f;
      float scale = (float)(Hh - 1) / (float)(H - 1);
      for (int h = 0; h < H; h++){
        float ysv = (float)h * scale;
        float y0f = floorf(ysv);
        int y0 = (int)y0f;
        float fy = ysv - y0f;
        int y1 = min(y0 + 1, Hh - 1);
        if (y0 == t) rs += 1.0f - fy;
        if (y1 == t) rs += fy;
      }
      out[t] = rs;
    }
    return;
  }
  int nb = blk - 7200;   // 0..671
  const float* xs; float* xd; int HW; int rb;
  if (nb < 512){ xs = x0; xd = xn0; HW = 4096; rb = nb; }
  else if (nb < 640){ xs = x1; xd = xn1; HW = 1024; rb = nb - 512; }
  else { xs = x2; xd = xn2; HW = 256; rb = nb - 640; }
  int p0 = rb * 32;
  int b = p0 / HW;
  int rem0 = p0 - b * HW;
  int pl = t & 31, cg = t >> 5;
  for (int ci = 0; ci < 32; ci++){
    int c = ci * 8 + cg;
    lds[pl][c] = xs[(long)(b * CH + c) * HW + rem0 + pl];
  }
  __syncthreads();
  for (int p = 0; p < 32; p++){
    xd[(long)(b * HW + rem0 + p) * CH + t] = lds[p][t];
  }
}

// ---------------- offset conv (all levels fused), 4-lane/pixel gather ---------
__global__ __launch_bounds__(256, 4) void conv_offset_mfma_kernel(
    const float* __restrict__ xn0, const float* __restrict__ xn1, const float* __restrict__ xn2,
    const unsigned short* __restrict__ W27, const float* __restrict__ boff,
    float* __restrict__ offs_all, float* __restrict__ mask_all){
  __shared__ __align__(16) short awlds[1024];
  __shared__ __align__(16) short cbuf[4096];
  int blk = blockIdx.x;
  const float* xn; int H; long ooff, moff; int rb;
  if (blk < 256){ xn = xn0; H = 64; ooff = 0; moff = 0; rb = blk; }
  else if (blk < 320){ xn = xn1; H = 32; ooff = 294912; moff = 147456; rb = blk - 256; }
  else { xn = xn2; H = 16; ooff = 368640; moff = 184320; rb = blk - 320; }
  int W = H, HW = H * W;
  int t = threadIdx.x;
  int lane = t & 63, wv = t >> 6;
  int pxp = t >> 2, cgp = t & 3;
  int pg = rb * 64 + pxp;
  int b = pg / HW;
  int rem = pg - b * HW;
  int i = rem / W, j = rem - i * W;

  f32x4 acc[2];
  #pragma unroll
  for (int mf = 0; mf < 2; mf++){
    #pragma unroll
    for (int r = 0; r < 4; r++){
      int o = mf * 16 + (lane >> 4) * 4 + r;
      acc[mf][r] = boff[o < 27 ? o : 0];
    }
  }

  for (int kk = 0; kk < 9; kk++){
    int ky = kk / 3, kx = kk - ky * 3;
    int ii = i - 1 + ky, jj = j - 1 + kx;
    bool valid = (ii >= 0 && ii < H && jj >= 0 && jj < W);
    int addr = valid ? ((b * HW + ii * W + jj) << 8) : 0;
    float vm = valid ? 1.0f : 0.0f;
    for (int cb8 = 0; cb8 < 8; cb8++){
      __syncthreads();
      const unsigned short* tile = W27 + (size_t)(kk * 8 + cb8) * 1024;
      if (t < 128) gload_lds16(tile + (t >> 6) * 512 + (t & 63) * 8, (short*)awlds + (t >> 6) * 512);
      const float* xc = xn + addr + cb8 * 32 + cgp * 8;
      float4 va = *(const float4*)xc;
      float4 vb = *(const float4*)(xc + 4);
      short8 pk;
      pk[0] = (short)f2bf(vm * va.x); pk[1] = (short)f2bf(vm * va.y);
      pk[2] = (short)f2bf(vm * va.z); pk[3] = (short)f2bf(vm * va.w);
      pk[4] = (short)f2bf(vm * vb.x); pk[5] = (short)f2bf(vm * vb.y);
      pk[6] = (short)f2bf(vm * vb.z); pk[7] = (short)f2bf(vm * vb.w);
      *(short8*)((char*)cbuf + pxp * 64 + ((cgp ^ ((pxp >> 1) & 3)) << 4)) = pk;
      __syncthreads();
      short8 af[2];
      #pragma unroll
      for (int mf = 0; mf < 2; mf++){
        int o = mf * 16 + (lane & 15);
        af[mf] = *(const short8*)((const char*)awlds + o * 64 + ((((lane >> 4)) ^ ((o >> 1) & 3)) << 4));
      }
      int nc = wv * 16 + (lane & 15);
      short8 bf1 = *(const short8*)((const char*)cbuf + nc * 64 + ((((lane >> 4)) ^ ((nc >> 1) & 3)) << 4));
      acc[0] = __builtin_amdgcn_mfma_f32_16x16x32_bf16(af[0], bf1, acc[0], 0, 0, 0);
      acc[1] = __builtin_amdgcn_mfma_f32_16x16x32_bf16(af[1], bf1, acc[1], 0, 0, 0);
    }
  }

  int rem0 = rb * 64 - b * HW;
  #pragma unroll
  for (int mf = 0; mf < 2; mf++){
    #pragma unroll
    for (int r = 0; r < 4; r++){
      int o = mf * 16 + (lane >> 4) * 4 + r;
      int pix = rem0 + wv * 16 + (lane & 15);
      float v = acc[mf][r];
      if (o < 18) offs_all[ooff + ((long)b * 18 + o) * HW + pix] = v;
      else if (o < 27) mask_all[moff + ((long)b * 9 + (o - 18)) * HW + pix] = 1.0f / (1.0f + expf(-v));
    }
  }
}

// ---------------- mdcn: 128px/512thr, weights->VGPR, 2-step phases, bf16 y ----
__device__ const int MJ_start[8] = {0,128,160,168,200,208,240,248};
__device__ const int MJ_xsel[7]  = {0,1,2,0,1,1,2};
__device__ const int MJ_Hx[7]    = {64,32,16,64,32,32,16};
__device__ const int MJ_ooff[7]  = {0,294912,368640,294912,368640,0,294912};
__device__ const int MJ_moff[7]  = {0,147456,184320,147456,184320,0,147456};
__device__ const int MJ_Hoff[7]  = {64,32,16,32,16,64,32};
__device__ const int MJ_ostep[7] = {1,1,1,1,1,2,2};
__device__ const int MJ_strd[7]  = {1,1,1,2,2,1,1};
__device__ const int MJ_wsel[7]  = {0,0,0,1,1,2,2};
__device__ const int MJ_yoff[7]  = {0,5242880,7602176,6291456,7864320,4194304,7340032};
__device__ const int MJ_Ho[7]    = {64,32,16,32,16,32,16};

__global__ __launch_bounds__(512, 2) void mdcn_mfma_kernel(
    const float* __restrict__ xn0, const float* __restrict__ xn1, const float* __restrict__ xn2,
    const float* __restrict__ offs_all, const float* __restrict__ mask_all,
    const unsigned short* __restrict__ Wm, const unsigned short* __restrict__ Wl, const unsigned short* __restrict__ Wh,
    unsigned short* __restrict__ y_all){
  __shared__ __align__(16) short colbuf[4][4096];  // 4 x 8 KB  B [128 px][32 kc]

  int dd = (blockIdx.x & 7) * 31 + (blockIdx.x >> 3);
  int job = 0;
  while (job < 6 && dd >= MJ_start[job + 1]) job++;
  int xsel = MJ_xsel[job];
  const float* xn = (xsel == 0) ? xn0 : (xsel == 1 ? xn1 : xn2);
  int wsel = MJ_wsel[job];
  const unsigned short* W3 = (wsel == 0) ? Wm : (wsel == 1 ? Wl : Wh);
  int Hx = MJ_Hx[job], Wx = Hx, HxWx = Hx * Hx;
  int Ho = MJ_Ho[job], Wo = Ho, HoWo = Ho * Ho;
  int Woff = MJ_Hoff[job], HoffW = Woff * Woff;
  int ostep = MJ_ostep[job], stride = MJ_strd[job];
  const float* offs = offs_all + MJ_ooff[job];
  const float* maskb = mask_all + MJ_moff[job];
  unsigned short* y = y_all + MJ_yoff[job];

  int rb = dd - MJ_start[job];
  int blkPerB = HoWo >> 7;
  int b = rb / blkPerB;
  int n0 = (rb - b * blkPerB) << 7;

  int t = threadIdx.x;
  int lane = t & 63;
  int wv = t >> 6;
  int wq = wv >> 1;
  int px = t >> 2;
  int cg = t & 3;

  int pix = n0 + px;
  int i = pix / Wo, j = pix - i * Wo;
  int opos = i * ostep * Woff + j * ostep;
  int base = b * HxWx;

  int4 A4c, A4n; float4 Wtc, Wtn;
  auto computeAW = [&](int kk, int4& A4o, float4& Wto){
    int ky = kk / 3, kx = kk - ky * 3;
    float offy = offs[((long)b * 18 + 2 * kk) * HoffW + opos];
    float offx = offs[((long)b * 18 + 2 * kk + 1) * HoffW + opos];
    float m = maskb[((long)b * 9 + kk) * HoffW + opos];
    float py = (float)(i * stride - 1 + ky) + offy;
    float pxx = (float)(j * stride - 1 + kx) + offx;
    float y0f = floorf(py), x0f = floorf(pxx);
    float fy = py - y0f, fx = pxx - x0f;
    bool vy0 = (y0f >= 0.0f) && (y0f <= (float)(Hx - 1));
    bool vy1 = (y0f + 1.0f >= 0.0f) && (y0f + 1.0f <= (float)(Hx - 1));
    bool vx0 = (x0f >= 0.0f) && (x0f <= (float)(Wx - 1));
    bool vx1 = (x0f + 1.0f >= 0.0f) && (x0f + 1.0f <= (float)(Wx - 1));
    float w0 = (1.0f - fy) * (1.0f - fx) * m * ((vy0 && vx0) ? 1.0f : 0.0f);
    float w1 = (1.0f - fy) * fx * m * ((vy0 && vx1) ? 1.0f : 0.0f);
    float w2 = fy * (1.0f - fx) * m * ((vy1 && vx0) ? 1.0f : 0.0f);
    float w3 = fy * fx * m * ((vy1 && vx1) ? 1.0f : 0.0f);
    int iy0 = min(max((int)y0f, 0), Hx - 1);
    int iy1 = min(max((int)y0f + 1, 0), Hx - 1);
    int ix0 = min(max((int)x0f, 0), Wx - 1);
    int ix1 = min(max((int)x0f + 1, 0), Wx - 1);
    A4o = make_int4((base + iy0 * Wx + ix0) << 8, (base + iy0 * Wx + ix1) << 8,
                    (base + iy1 * Wx + ix0) << 8, (base + iy1 * Wx + ix1) << 8);
    Wto = make_float4(w0, w1, w2, w3);
  };

  float4 g0_0,g0_1,g0_2,g0_3,g0_4,g0_5,g0_6,g0_7;
  float4 g1_0,g1_1,g1_2,g1_3,g1_4,g1_5,g1_6,g1_7;

  short8 af0[4], af1[4];
  auto loadA = [&](int s, short8* af){
    const short8* wp = (const short8*)W3 + ((size_t)s * 16 + wq * 4) * 64 + lane;
    af[0] = wp[0]; af[1] = wp[64]; af[2] = wp[128]; af[3] = wp[192];
  };

  f32x4 acc[4][4];
  #pragma unroll
  for (int mf = 0; mf < 4; mf++)
    #pragma unroll
    for (int nf = 0; nf < 4; nf++)
      acc[mf][nf] = (f32x4){0.f, 0.f, 0.f, 0.f};

#define GATHER_(P, CB, A4G) do{ \
    const float* xc_ = xn + (CB)*32 + cg*8; \
    g##P##_0 = *(const float4*)(xc_ + (A4G).x); g##P##_1 = *(const float4*)(xc_ + (A4G).x + 4); \
    g##P##_2 = *(const float4*)(xc_ + (A4G).y); g##P##_3 = *(const float4*)(xc_ + (A4G).y + 4); \
    g##P##_4 = *(const float4*)(xc_ + (A4G).z); g##P##_5 = *(const float4*)(xc_ + (A4G).z + 4); \
    g##P##_6 = *(const float4*)(xc_ + (A4G).w); g##P##_7 = *(const float4*)(xc_ + (A4G).w + 4); \
  }while(0)

#define PACKW_(P, BUF, WT) do{ \
    short8 pk_; \
    pk_[0] = (short)f2bf((WT).x*g##P##_0.x + (WT).y*g##P##_2.x + (WT).z*g##P##_4.x + (WT).w*g##P##_6.x); \
    pk_[1] = (short)f2bf((WT).x*g##P##_0.y + (WT).y*g##P##_2.y + (WT).z*g##P##_4.y + (WT).w*g##P##_6.y); \
    pk_[2] = (short)f2bf((WT).x*g##P##_0.z + (WT).y*g##P##_2.z + (WT).z*g##P##_4.z + (WT).w*g##P##_6.z); \
    pk_[3] = (short)f2bf((WT).x*g##P##_0.w + (WT).y*g##P##_2.w + (WT).z*g##P##_4.w + (WT).w*g##P##_6.w); \
    pk_[4] = (short)f2bf((WT).x*g##P##_1.x + (WT).y*g##P##_3.x + (WT).z*g##P##_5.x + (WT).w*g##P##_7.x); \
    pk_[5] = (short)f2bf((WT).x*g##P##_1.y + (WT).y*g##P##_3.y + (WT).z*g##P##_5.y + (WT).w*g##P##_7.y); \
    pk_[6] = (short)f2bf((WT).x*g##P##_1.z + (WT).y*g##P##_3.z + (WT).z*g##P##_5.z + (WT).w*g##P##_7.z); \
    pk_[7] = (short)f2bf((WT).x*g##P##_1.w + (WT).y*g##P##_3.w + (WT).z*g##P##_5.w + (WT).w*g##P##_7.w); \
    *(short8*)((char*)colbuf[BUF] + px * 64 + ((cg ^ ((px >> 1) & 3)) << 4)) = pk_; \
  }while(0)

#define MFMA_(BUF, AF) do{ \
    __builtin_amdgcn_s_setprio(1); \
    short8 bf_[4]; \
    _Pragma("unroll") \
    for (int nf = 0; nf < 4; nf++){ \
      int nc_ = (wv & 1) * 64 + nf * 16 + (lane & 15); \
      bf_[nf] = *(const short8*)((const char*)colbuf[BUF] + nc_ * 64 + ((((lane >> 4)) ^ ((nc_ >> 1) & 3)) << 4)); } \
    _Pragma("unroll") \
    for (int mf = 0; mf < 4; mf++) \
      _Pragma("unroll") \
      for (int nf = 0; nf < 4; nf++) \
        acc[mf][nf] = __builtin_amdgcn_mfma_f32_16x16x32_bf16((AF)[mf], bf_[nf], acc[mf][nf], 0, 0, 0); \
    __builtin_amdgcn_s_setprio(0); \
  }while(0)

#define BARRIER_ do{ \
    asm volatile("s_waitcnt lgkmcnt(0)" ::: "memory"); \
    __builtin_amdgcn_sched_barrier(0); \
    __builtin_amdgcn_s_barrier(); \
    __builtin_amdgcn_sched_barrier(0); \
  }while(0)

#define PHASE_(P, PC, PN) do{ \
    if ((P) <= 34){ PACKW_(0, (PN), Wtc); PACKW_(1, (PN)+1, Wtc); } \
    if ((P) <= 33){ \
      if (((2*(P)+4) & 7) == 0){ \
        computeAW((2*(P)+4) >> 3, A4n, Wtn); \
        GATHER_(0, 0, A4n); \
        GATHER_(1, 1, A4n); \
      } else { \
        GATHER_(0, (2*(P)+4) & 7, A4c); \
        GATHER_(1, (2*(P)+5) & 7, A4c); \
      } \
    } \
    MFMA_((PC), af0); \
    MFMA_((PC)+1, af1); \
    if ((P) <= 34){ loadA(2*(P)+2, af0); loadA(2*(P)+3, af1); } \
    if ((P) <= 33 && ((2*(P)+4) & 7) == 0){ A4c = A4n; Wtc = Wtn; } \
    BARRIER_; \
  }while(0)

  computeAW(0, A4c, Wtc);
  loadA(0, af0);
  loadA(1, af1);
  GATHER_(0, 0, A4c);
  GATHER_(1, 1, A4c);
  PACKW_(0, 0, Wtc);
  PACKW_(1, 1, Wtc);
  GATHER_(0, 2, A4c);
  GATHER_(1, 3, A4c);
  BARRIER_;

  for (int pp = 0; pp < 36; pp += 2){
    PHASE_(pp, 0, 2);
    PHASE_(pp + 1, 2, 0);
  }

#undef PHASE_
#undef BARRIER_
#undef MFMA_
#undef PACKW_
#undef GATHER_

  #pragma unroll
  for (int mf = 0; mf < 4; mf++){
    #pragma unroll
    for (int nf = 0; nf < 4; nf++){
      #pragma unroll
      for (int r = 0; r < 4; r++){
        int o = wq * 64 + mf * 16 + (lane >> 4) * 4 + r;
        int pix2 = n0 + (wv & 1) * 64 + nf * 16 + (lane & 15);
        y[((long)b * CH + o) * HoWo + pix2] = f2bf(acc[mf][nf][r]);
      }
    }
  }
}

// ---------------- stats over all 7 tensors, fused, bf16 short8 loads ----------
__device__ const int SJ_yoff[7] = {0,4194304,5242880,6291456,7340032,7602176,7864320};
__device__ const int SJ_HW[7]   = {4096,1024,1024,1024,256,256,256};
__device__ const int SJ_rw[7]   = {0,1,0,0,2,0,0};

__global__ __launch_bounds__(256) void stats_all_kernel(
    const unsigned short* __restrict__ y_all, const float* __restrict__ roww0, const float* __restrict__ roww1,
    float* __restrict__ sums_all, float* __restrict__ ss_all, float* __restrict__ wsum_all){
  int blk = blockIdx.x;
  int job = blk >> 10, bc = blk & 1023;
  int HW = SJ_HW[job];
  int Ws = (HW == 4096) ? 64 : ((HW == 1024) ? 32 : 16);
  int rwsel = SJ_rw[job];
  const float* rw = (rwsel == 2) ? roww1 : roww0;
  const unsigned short* p = y_all + SJ_yoff[job] + (long)bc * HW;
  int t = threadIdx.x;
  float s = 0, ss = 0, ws = 0;
  for (int e0 = t * 8; e0 < HW; e0 += 2048){
    short8 v8 = *(const short8*)(p + e0);
    float vv[8];
    #pragma unroll
    for (int jj = 0; jj < 8; jj++) vv[jj] = bf2f((unsigned short)v8[jj]);
    #pragma unroll
    for (int jj = 0; jj < 8; jj++){ s += vv[jj]; ss += vv[jj] * vv[jj]; }
    if (rwsel){
      int r = e0 / Ws, cc = e0 - r * Ws;
      float rr = rw[r];
      float rsum = 0;
      #pragma unroll
      for (int jj = 0; jj < 8; jj++) rsum += vv[jj] * rw[cc + jj];
      ws += rr * rsum;
    }
  }
  __shared__ float r1[256], r2[256], r3[256];
  r1[t] = s; r2[t] = ss; r3[t] = ws;
  __syncthreads();
  for (int o = 128; o > 0; o >>= 1){
    if (t < o){ r1[t] += r1[t + o]; r2[t] += r2[t + o]; r3[t] += r3[t + o]; }
    __syncthreads();
  }
  if (t == 0){
    sums_all[job * 1024 + bc] = r1[0];
    ss_all[job * 1024 + bc] = r2[0];
    if (rwsel) wsum_all[(rwsel - 1) * 1024 + bc] = r3[0];
  }
}

// ---------------- group-norm stats + scale_attn, all 7 jobs fused -------------
__device__ const int   GJ_psrc[7] = {0,1,0,0,2,0,0};
__device__ const float GJ_pdiv[7] = {1.f/4096,1.f/4096,1.f/1024,1.f/1024,1.f/1024,1.f/256,1.f/256};
__device__ const float GJ_ninv[7] = {1.f/65536,1.f/16384,1.f/16384,1.f/16384,1.f/4096,1.f/4096,1.f/4096};
__device__ const int   GJ_gsel[7] = {0,2,0,1,2,0,1};

__global__ __launch_bounds__(256) void gn_sa_all_kernel(
    const float* __restrict__ sums_all, const float* __restrict__ ss_all, const float* __restrict__ wsum_all,
    const float* __restrict__ gw_m, const float* __restrict__ gb_m,
    const float* __restrict__ gw_l, const float* __restrict__ gb_l,
    const float* __restrict__ gw_h, const float* __restrict__ gb_h,
    const float* __restrict__ saw, const float* __restrict__ sab,
    float* __restrict__ mu_all, float* __restrict__ rs_all, float* __restrict__ v_all){
  int blk = blockIdx.x;
  int job = blk >> 2, b = blk & 3;
  int t = threadIdx.x;
  const float* sums = sums_all + job * 1024;
  const float* ssq  = ss_all + job * 1024;
  int psrc = GJ_psrc[job];
  const float* ps = (psrc == 0) ? sums : (wsum_all + (psrc - 1) * 1024);
  int gsel = GJ_gsel[job];
  const float* gw = (gsel == 0) ? gw_m : (gsel == 1 ? gw_l : gw_h);
  const float* gb = (gsel == 0) ? gb_m : (gsel == 1 ? gb_l : gb_h);
  float pdiv = GJ_pdiv[job], ninv = GJ_ninv[job];
  __shared__ float smu[GRP], srs[GRP], red[256];
  if (t < GRP){
    float s = 0, ss = 0;
    for (int c = 0; c < 16; c++){ int idx = b * CH + t * 16 + c; s += sums[idx]; ss += ssq[idx]; }
    float mu = s * ninv;
    float var = ss * ninv - mu * mu;
    float rs = rsqrtf(var + EPSV);
    smu[t] = mu; srs[t] = rs;
    mu_all[job * 64 + b * GRP + t] = mu;
    rs_all[job * 64 + b * GRP + t] = rs;
  }
  __syncthreads();
  int g = t >> 4;
  float pm = (ps[b * CH + t] * pdiv - smu[g]) * srs[g] * gw[t] + gb[t];
  red[t] = pm * saw[t];
  __syncthreads();
  for (int o = 128; o > 0; o >>= 1){ if (t < o) red[t] += red[t + o]; __syncthreads(); }
  if (t == 0) v_all[job * 4 + b] = hsig(fmaxf(red[0] + sab[0], 0.0f));
}

// GN-stat slot numbering: 0=mid0, 1=high0, 2=mid1, 3=low1, 4=high1, 5=mid2, 6=low2
__device__ const long CA_yb[3] = {0, 5242880, 7602176};
__device__ const long CA_yl[3] = {0, 6291456, 7864320};
__device__ const long CA_yh[3] = {4194304, 7340032, 0};
__device__ const int  CA_ms[3] = {0, 2, 5};
__device__ const int  CA_ls[3] = {0, 3, 6};
__device__ const int  CA_hs[3] = {1, 4, 0};
__device__ const long FA_out[3] = {0, 4194304, 5242880};

// ---------------- dyrelu coefficients computed analytically -------------------
__global__ __launch_bounds__(256) void dyrelu_direct_kernel(
    const float* __restrict__ sums_all, const float* __restrict__ wsum_all,
    const float* __restrict__ mu_all, const float* __restrict__ rs_all, const float* __restrict__ v_all,
    const float* __restrict__ gw_m, const float* __restrict__ gb_m,
    const float* __restrict__ gw_l, const float* __restrict__ gb_l,
    const float* __restrict__ gw_h, const float* __restrict__ gb_h,
    const float* __restrict__ w1, const float* __restrict__ b1,
    const float* __restrict__ w2, const float* __restrict__ b2,
    float* __restrict__ coef_all){
  int lvl = blockIdx.x >> 2, b = blockIdx.x & 3;
  int t = threadIdx.x;
  int H = 64 >> lvl, HW = H * H;
  float invHW = 1.0f / (float)HW;
  int has_lo = (lvl > 0), has_hi = (lvl < 2);
  float inv_cnt = 1.0f / (1.0f + has_lo + has_hi);
  int ms = CA_ms[lvl], ls = CA_ls[lvl], hs = CA_hs[lvl];
  int g = t >> 4;
  float p = v_all[ms * 4 + b] *
      ((sums_all[ms * 1024 + b * CH + t] * invHW - mu_all[ms * 64 + b * GRP + g]) * rs_all[ms * 64 + b * GRP + g] * gw_m[t] + gb_m[t]);
  if (has_lo)
    p += v_all[ls * 4 + b] *
      ((sums_all[ls * 1024 + b * CH + t] * invHW - mu_all[ls * 64 + b * GRP + g]) * rs_all[ls * 64 + b * GRP + g] * gw_l[t] + gb_l[t]);
  if (has_hi)
    p += v_all[hs * 4 + b] *
      ((wsum_all[lvl * 1024 + b * CH + t] * invHW - mu_all[hs * 64 + b * GRP + g]) * rs_all[hs * 64 + b * GRP + g] * gw_h[t] + gb_h[t]);
  p *= inv_cnt;
  __shared__ float pl[CH], hl[64];
  pl[t] = p;
  __syncthreads();
  if (t < 64){
    float a = b1[t];
    const float* wr = w1 + t * CH;
    for (int c = 0; c < CH; c++) a += wr[c] * pl[c];
    hl[t] = fmaxf(a, 0.0f);
  }
  __syncthreads();
  #pragma unroll
  for (int r = 0; r < 4; r++){
    int o = r * CH + t;
    float a = b2[o];
    const float* wr = w2 + o * 64;
    #pragma unroll
    for (int j = 0; j < 64; j++) a += wr[j] * hl[j];
    float co = hsig(a) - 0.5f;
    float outv;
    if (r == 0) outv = co * 2.0f + 1.0f;
    else if (r == 2) outv = co * 2.0f;
    else outv = co;
    coef_all[lvl * 4096 + (b * 4 + r) * CH + t] = outv;
  }
}

// ---------------- combine + dyrelu apply, fused, bf16 reads (4 px/thread) -----
__global__ __launch_bounds__(256) void combine_final_kernel(
    const unsigned short* __restrict__ y_all,
    const float* __restrict__ mu_all, const float* __restrict__ rs_all, const float* __restrict__ v_all,
    const float* __restrict__ gw_m, const float* __restrict__ gb_m,
    const float* __restrict__ gw_l, const float* __restrict__ gb_l,
    const float* __restrict__ gw_h, const float* __restrict__ gb_h,
    const float* __restrict__ coef_all, float* __restrict__ outp){
  int blk = blockIdx.x;
  int lvl, rb;
  if (blk < 4096){ lvl = 0; rb = blk; }
  else if (blk < 5120){ lvl = 1; rb = blk - 4096; }
  else { lvl = 2; rb = blk - 5120; }
  int H = 64 >> lvl, W = H, HW = H * W;
  int has_lo = (lvl > 0), has_hi = (lvl < 2);
  float inv_cnt = 1.0f / (1.0f + has_lo + has_hi);
  int ms = CA_ms[lvl], ls = CA_ls[lvl], hs = CA_hs[lvl];
  const unsigned short* smid = y_all + CA_yb[lvl];
  const unsigned short* ylo = y_all + CA_yl[lvl];
  const unsigned short* yhi = y_all + CA_yh[lvl];

  int t = threadIdx.x;
  int idx = (rb * 256 + t) * 4;
  int b = idx / (CH * HW);
  int r1i = idx - b * CH * HW;
  int c = r1i / HW;
  int rem = r1i - c * HW;
  int h = rem / W;
  int w = rem - h * W;
  int g = c >> 4;
  int bg = b * GRP + g;

  short4v m4 = *(const short4v*)(smid + idx);
  float vms = v_all[ms * 4 + b], mum = mu_all[ms * 64 + bg], rsm = rs_all[ms * 64 + bg];
  float gm = gw_m[c], bm = gb_m[c];
  float4 s4;
  s4.x = vms * ((bf2f((unsigned short)m4[0]) - mum) * rsm * gm + bm);
  s4.y = vms * ((bf2f((unsigned short)m4[1]) - mum) * rsm * gm + bm);
  s4.z = vms * ((bf2f((unsigned short)m4[2]) - mum) * rsm * gm + bm);
  s4.w = vms * ((bf2f((unsigned short)m4[3]) - mum) * rsm * gm + bm);
  if (has_lo){
    short4v l4 = *(const short4v*)(ylo + idx);
    float vls = v_all[ls * 4 + b], mul = mu_all[ls * 64 + bg], rsl = rs_all[ls * 64 + bg];
    float gl = gw_l[c], bl = gb_l[c];
    s4.x += vls * ((bf2f((unsigned short)l4[0]) - mul) * rsl * gl + bl);
    s4.y += vls * ((bf2f((unsigned short)l4[1]) - mul) * rsl * gl + bl);
    s4.z += vls * ((bf2f((unsigned short)l4[2]) - mul) * rsl * gl + bl);
    s4.w += vls * ((bf2f((unsigned short)l4[3]) - mul) * rsl * gl + bl);
  }
  if (has_hi){
    int Hh = H >> 1, Wh = W >> 1;
    float ysv = (float)h * ((float)(Hh - 1) / (float)(H - 1));
    float y0f = floorf(ysv); int y0 = (int)y0f; float fy = ysv - y0f; int y1 = min(y0 + 1, Hh - 1);
    const unsigned short* hb = yhi + (long)(b * CH + c) * Hh * Wh;
    float vhs = v_all[hs * 4 + b], muh = mu_all[hs * 64 + bg], rsh = rs_all[hs * 64 + bg];
    float gh = gw_h[c], bh = gb_h[c];
    float xscale = (float)(Wh - 1) / (float)(W - 1);
    float* sp = (float*)&s4;
    #pragma unroll
    for (int dw = 0; dw < 4; dw++){
      float xsv = (float)(w + dw) * xscale;
      float x0f = floorf(xsv); int x0 = (int)x0f; float fx = xsv - x0f; int x1 = min(x0 + 1, Wh - 1);
      float v00 = bf2f(hb[y0 * Wh + x0]), v01 = bf2f(hb[y0 * Wh + x1]);
      float v10 = bf2f(hb[y1 * Wh + x0]), v11 = bf2f(hb[y1 * Wh + x1]);
      float blv = v00 * (1 - fy) * (1 - fx) + v01 * (1 - fy) * fx + v10 * fy * (1 - fx) + v11 * fy * fx;
      sp[dw] += vhs * ((blv - muh) * rsh * gh + bh);
    }
  }
  const float* cf = coef_all + lvl * 4096 + b * 4 * CH;
  float a1 = cf[c], c1 = cf[CH + c], a2 = cf[2 * CH + c], c2 = cf[3 * CH + c];
  float4 o4;
  float sx = s4.x * inv_cnt, sy = s4.y * inv_cnt, sz = s4.z * inv_cnt, sw = s4.w * inv_cnt;
  o4.x = fmaxf(sx * a1 + c1, sx * a2 + c2);
  o4.y = fmaxf(sy * a1 + c1, sy * a2 + c2);
  o4.z = fmaxf(sz * a1 + c1, sz * a2 + c2);
  o4.w = fmaxf(sw * a1 + c1, sw * a2 + c2);
  *(float4*)(outp + FA_out[lvl] + idx) = o4;
}

extern "C" void kernel_launch(void* const* d_in, const int* in_sizes, int n_in,
                              void* d_out, int out_size, void* d_ws, size_t ws_size,
                              hipStream_t stream){
  const float* x0 = (const float*)d_in[0];
  const float* x1 = (const float*)d_in[1];
  const float* x2 = (const float*)d_in[2];
  const float* w_off = (const float*)d_in[3];
  const float* b_off = (const float*)d_in[4];
  int sig = (in_sizes[6] == 256);
  const float* w_high = (const float*)d_in[5];
  const float* w_mid  = (const float*)d_in[sig ? 8 : 6];
  const float* w_low  = (const float*)d_in[sig ? 11 : 7];
  const float* gn_high_w = (const float*)d_in[sig ? 6 : 8];
  const float* gn_high_b = (const float*)d_in[sig ? 7 : 9];
  const float* gn_mid_w  = (const float*)d_in[sig ? 9 : 10];
  const float* gn_mid_b  = (const float*)d_in[sig ? 10 : 11];
  const float* gn_low_w  = (const float*)d_in[12];
  const float* gn_low_b  = (const float*)d_in[13];
  const float* sa_w  = (const float*)d_in[14];
  const float* sa_b  = (const float*)d_in[15];
  const float* dy_w1 = (const float*)d_in[16];
  const float* dy_b1 = (const float*)d_in[17];
  const float* dy_w2 = (const float*)d_in[18];
  const float* dy_b2 = (const float*)d_in[19];

  float* p = (float*)d_ws;
  unsigned short* W3_mid  = (unsigned short*)p; p += 294912;
  unsigned short* W3_low  = (unsigned short*)p; p += 294912;
  unsigned short* W3_high = (unsigned short*)p; p += 294912;
  unsigned short* W27     = (unsigned short*)p; p += 36864;
  float* xn0 = p; p += 4194304;
  float* xn1 = p; p += 1048576;
  float* xn2 = p; p += 262144;
  float* offs_all = p; p += 387072;
  float* mask_all = p; p += 193536;
  unsigned short* y_all = (unsigned short*)p; p += 4063232;   // 8126464 bf16 elems
  float* sums_all = p; p += 7168;
  float* ss_all = p; p += 7168;
  float* wsum_all = p; p += 2048;
  float* coef_all = p; p += 12288;
  float* mu_all = p; p += 448;
  float* rs_all = p; p += 448;
  float* v_all = p; p += 28;   p += 4;  // align
  float* roww0 = p; p += 32;
  float* roww1 = p; p += 32;

  prep_kernel<<<7874, 256, 0, stream>>>(w_mid, w_low, w_high, w_off, x0, x1, x2,
                                        W3_mid, W3_low, W3_high, W27,
                                        xn0, xn1, xn2, roww0, roww1);
  conv_offset_mfma_kernel<<<336, 256, 0, stream>>>(xn0, xn1, xn2, W27, b_off, offs_all, mask_all);
  mdcn_mfma_kernel<<<248, 512, 0, stream>>>(xn0, xn1, xn2, offs_all, mask_all, W3_mid, W3_low, W3_high, y_all);
  stats_all_kernel<<<7168, 256, 0, stream>>>(y_all, roww0, roww1, sums_all, ss_all, wsum_all);
  gn_sa_all_kernel<<<28, 256, 0, stream>>>(sums_all, ss_all, wsum_all,
                                           gn_mid_w, gn_mid_b, gn_low_w, gn_low_b, gn_high_w, gn_high_b,
                                           sa_w, sa_b, mu_all, rs_all, v_all);
  dyrelu_direct_kernel<<<12, 256, 0, stream>>>(sums_all, wsum_all, mu_all, rs_all, v_all,
                                               gn_mid_w, gn_mid_b, gn_low_w, gn_low_b, gn_high_w, gn_high_b,
                                               dy_w1, dy_b1, dy_w2, dy_b2, coef_all);
  combine_final_kernel<<<5376, 256, 0, stream>>>(y_all, mu_all, rs_all, v_all,
                                                 gn_mid_w, gn_mid_b, gn_low_w, gn_low_b, gn_high_w, gn_high_b,
                                                 coef_all, (float*)d_out);
}